// Round 1
// baseline (113.397 us; speedup 1.0000x reference)
//
#include <hip/hip_runtime.h>

typedef _Float16 half8 __attribute__((ext_vector_type(8)));
typedef float f32x4 __attribute__((ext_vector_type(4)));

#define S_LEN 2048
#define HDIM 64
#define QBLK 64
#define KVBLK 64
#define QRS 258   // qrel row stride (elements)

// One block = 4 waves, 64 q-rows of one (b,h); wave w owns rows [w*16, w*16+16).
// LDS: K tile (swizzled), V tile transposed (swizzled), per-wave P buffer, qrel table.
__global__ __launch_bounds__(256, 2)
void relattn_kernel(const float* __restrict__ Qg, const float* __restrict__ Kg,
                    const float* __restrict__ Vg, const float* __restrict__ RELg,
                    float* __restrict__ Og)
{
    __shared__ _Float16 Klds[KVBLK * HDIM];        // 8 KB, element (kv,d) at byte (kv*128+d*2)^((kv&7)<<4)
    __shared__ _Float16 Vt[HDIM * KVBLK];          // 8 KB, element (d,kv) at byte (d*128+kv*2)^((d&7)<<4)
    __shared__ _Float16 Plds[4][16 * KVBLK];       // 8 KB, per-wave, (r,kv) at byte (r*128+kv*2)^((r&7)<<4)
    __shared__ _Float16 Qrel[QBLK * QRS];          // 33 KB, qrel[row][idx], idx in [0,256]

    const int tid  = threadIdx.x;
    const int wave = tid >> 6;
    const int lane = tid & 63;
    const int c = lane & 15;      // col-within-16 (MFMA lane%16)
    const int g = lane >> 4;      // MFMA lane/16

    const int bid = blockIdx.x;
    const int bh  = bid >> 5;               // 32 q-tiles per head
    const int q0  = (bid & 31) * QBLK;

    const size_t hoff = (size_t)bh * S_LEN * HDIM;
    const float* Qh = Qg + hoff;
    const float* Kh = Kg + hoff;
    const float* Vh = Vg + hoff;

    // ---- Q fragments (A-operand layout), pre-scaled by 1/sqrt(D)=0.125 (exact in fp16) ----
    const int qrow_frag = q0 + wave * 16 + c;
    half8 aq[2];
#pragma unroll
    for (int kc = 0; kc < 2; ++kc) {
        const float* src = Qh + (size_t)qrow_frag * HDIM + kc * 32 + g * 8;
        f32x4 f0 = *(const f32x4*)(src);
        f32x4 f1 = *(const f32x4*)(src + 4);
        half8 h;
#pragma unroll
        for (int j = 0; j < 4; ++j) {
            h[j]     = (_Float16)(f0[j] * 0.125f);
            h[j + 4] = (_Float16)(f1[j] * 0.125f);
        }
        aq[kc] = h;
    }

    // ---- qrel = (Q/8) @ rel_table^T via MFMA, per-wave rows, cols 0..256 ----
#pragma unroll 1
    for (int t = 0; t < 17; ++t) {
        f32x4 acc = {0.f, 0.f, 0.f, 0.f};
        int r = t * 16 + c;
        if (r > 256) r = 256;                 // clamp OOB table rows (cols>256 never stored)
#pragma unroll
        for (int kc = 0; kc < 2; ++kc) {
            const float* src = RELg + (size_t)r * HDIM + kc * 32 + g * 8;
            f32x4 f0 = *(const f32x4*)(src);
            f32x4 f1 = *(const f32x4*)(src + 4);
            half8 b;
#pragma unroll
            for (int j = 0; j < 4; ++j) {
                b[j]     = (_Float16)f0[j];
                b[j + 4] = (_Float16)f1[j];
            }
            acc = __builtin_amdgcn_mfma_f32_16x16x32_f16(aq[kc], b, acc, 0, 0, 0);
        }
        const int col = t * 16 + c;
        if (col <= 256) {
#pragma unroll
            for (int reg = 0; reg < 4; ++reg)
                Qrel[(wave * 16 + 4 * g + reg) * QRS + col] = (_Float16)acc[reg];
        }
    }
    // qrel is written and read only by the owning wave -> no barrier needed.

    float mrow[4], lrow[4];
    f32x4 oacc[4];
#pragma unroll
    for (int i = 0; i < 4; ++i) {
        mrow[i] = -1e30f; lrow[i] = 0.f;
        oacc[i] = (f32x4){0.f, 0.f, 0.f, 0.f};
    }

    for (int k0 = 0; k0 < S_LEN; k0 += KVBLK) {
        __syncthreads();   // previous iteration's readers done before restaging
        // ---- stage K tile (fp32 -> fp16, swizzled) ----
        {
            const int r  = tid >> 2;            // 0..63
            const int dq = (tid & 3) << 4;      // 0,16,32,48
            const float* src = Kh + (size_t)(k0 + r) * HDIM + dq;
            f32x4 f0 = *(const f32x4*)(src);
            f32x4 f1 = *(const f32x4*)(src + 4);
            f32x4 f2 = *(const f32x4*)(src + 8);
            f32x4 f3 = *(const f32x4*)(src + 12);
            half8 h0, h1;
#pragma unroll
            for (int j = 0; j < 4; ++j) {
                h0[j] = (_Float16)f0[j]; h0[j+4] = (_Float16)f1[j];
                h1[j] = (_Float16)f2[j]; h1[j+4] = (_Float16)f3[j];
            }
            const int swz = (r & 7) << 4;
            char* base = (char*)Klds;
            *(half8*)(base + ((r * 128 + dq * 2) ^ swz))      = h0;
            *(half8*)(base + ((r * 128 + dq * 2 + 16) ^ swz)) = h1;
        }
        // ---- stage V transposed (Vt[d][kv], swizzled) ----
        {
            const int kv = tid & 63;
            const int dbase = (tid >> 6) << 4;  // 0,16,32,48
            const float* src = Vh + (size_t)(k0 + kv) * HDIM + dbase;
            f32x4 f0 = *(const f32x4*)(src);
            f32x4 f1 = *(const f32x4*)(src + 4);
            f32x4 f2 = *(const f32x4*)(src + 8);
            f32x4 f3 = *(const f32x4*)(src + 12);
            float vals[16];
#pragma unroll
            for (int j = 0; j < 4; ++j) {
                vals[j] = f0[j]; vals[4+j] = f1[j]; vals[8+j] = f2[j]; vals[12+j] = f3[j];
            }
            char* base = (char*)Vt;
#pragma unroll
            for (int i = 0; i < 16; ++i) {
                const int d = dbase + i;
                const int off = (d * 128 + kv * 2) ^ ((d & 7) << 4);
                *(_Float16*)(base + off) = (_Float16)vals[i];
            }
        }
        __syncthreads();

        // ---- S = (Q/8) @ K^T : 4 col-tiles x 2 K-chunks ----
        f32x4 sacc[4];
#pragma unroll
        for (int n = 0; n < 4; ++n) sacc[n] = (f32x4){0.f,0.f,0.f,0.f};
#pragma unroll
        for (int kc = 0; kc < 2; ++kc) {
#pragma unroll
            for (int n = 0; n < 4; ++n) {
                const int off = (((16*n + c) * 128) + kc * 64 + g * 16) ^ ((c & 7) << 4);
                half8 bk = *(const half8*)((const char*)Klds + off);
                sacc[n] = __builtin_amdgcn_mfma_f32_16x16x32_f16(aq[kc], bk, sacc[n], 0, 0, 0);
            }
        }

        // ---- add rel bias (LDS gather from qrel) ----
        float sval[4][4];
        const int myq0 = q0 + wave * 16 + 4 * g;   // + reg gives global q row
#pragma unroll
        for (int n = 0; n < 4; ++n) {
            const int kpos = k0 + 16 * n + c;
#pragma unroll
            for (int reg = 0; reg < 4; ++reg) {
                int rel = kpos - (myq0 + reg);
                rel = rel < -128 ? -128 : (rel > 128 ? 128 : rel);
                const float bias = (float)Qrel[(wave*16 + 4*g + reg) * QRS + (rel + 128)];
                sval[n][reg] = sacc[n][reg] + bias;
            }
        }

        // ---- online softmax (per row; row lives in the 16-lane group sharing g) ----
        float mt[4];
#pragma unroll
        for (int reg = 0; reg < 4; ++reg) {
            float mp = fmaxf(fmaxf(sval[0][reg], sval[1][reg]),
                             fmaxf(sval[2][reg], sval[3][reg]));
#pragma unroll
            for (int msk = 1; msk < 16; msk <<= 1)
                mp = fmaxf(mp, __shfl_xor(mp, msk, 64));
            mt[reg] = mp;
        }

        float alpha[4], psum[4];
#pragma unroll
        for (int reg = 0; reg < 4; ++reg) {
            const float mn = fmaxf(mrow[reg], mt[reg]);
            alpha[reg] = __expf(mrow[reg] - mn);
            mrow[reg] = mn;
            psum[reg] = 0.f;
        }

        char* pbase = (char*)&Plds[wave][0];
#pragma unroll
        for (int n = 0; n < 4; ++n) {
#pragma unroll
            for (int reg = 0; reg < 4; ++reg) {
                const float pv = __expf(sval[n][reg] - mrow[reg]);
                psum[reg] += pv;
                const int row = 4 * g + reg;
                const int off = (row * 128 + (16 * n + c) * 2) ^ ((row & 7) << 4);
                *(_Float16*)(pbase + off) = (_Float16)pv;
            }
        }

#pragma unroll
        for (int reg = 0; reg < 4; ++reg) {
            float ps = psum[reg];
#pragma unroll
            for (int msk = 1; msk < 16; msk <<= 1)
                ps += __shfl_xor(ps, msk, 64);
            lrow[reg] = lrow[reg] * alpha[reg] + ps;
#pragma unroll
            for (int dn = 0; dn < 4; ++dn) oacc[dn][reg] *= alpha[reg];
        }

        // P writes are same-wave consumed; drain LDS queue before re-reading.
        asm volatile("s_waitcnt lgkmcnt(0)" ::: "memory");

        // ---- O += P @ V ----
        half8 ap[2];
#pragma unroll
        for (int kc = 0; kc < 2; ++kc) {
            const int off = (c * 128 + kc * 64 + g * 16) ^ ((c & 7) << 4);
            ap[kc] = *(const half8*)(pbase + off);
        }
#pragma unroll
        for (int kc = 0; kc < 2; ++kc) {
#pragma unroll
            for (int dn = 0; dn < 4; ++dn) {
                const int drow = 16 * dn + c;
                const int off = (drow * 128 + kc * 64 + g * 16) ^ ((c & 7) << 4);
                half8 bv = *(const half8*)((const char*)Vt + off);
                oacc[dn] = __builtin_amdgcn_mfma_f32_16x16x32_f16(ap[kc], bv, oacc[dn], 0, 0, 0);
            }
        }
    }

    // ---- epilogue: O / l ----
#pragma unroll
    for (int reg = 0; reg < 4; ++reg) {
        const float inv = 1.0f / lrow[reg];
        const int row = q0 + wave * 16 + 4 * g + reg;
        float* dst = Og + hoff + (size_t)row * HDIM + c;
#pragma unroll
        for (int dn = 0; dn < 4; ++dn)
            dst[16 * dn] = oacc[dn][reg] * inv;
    }
}

extern "C" void kernel_launch(void* const* d_in, const int* in_sizes, int n_in,
                              void* d_out, int out_size, void* d_ws, size_t ws_size,
                              hipStream_t stream) {
    const float* q   = (const float*)d_in[0];
    const float* k   = (const float*)d_in[1];
    const float* v   = (const float*)d_in[2];
    const float* rel = (const float*)d_in[3];
    float* out = (float*)d_out;
    (void)in_sizes; (void)n_in; (void)out_size; (void)d_ws; (void)ws_size;

    dim3 grid(16 * (S_LEN / QBLK));   // 16 heads x 32 q-tiles = 512 blocks
    relattn_kernel<<<grid, 256, 0, stream>>>(q, k, v, rel, out);
}

// Round 2
// 74.063 us; speedup vs baseline: 1.5311x; 1.5311x over previous
//
#include <hip/hip_runtime.h>

typedef _Float16 half8 __attribute__((ext_vector_type(8)));
typedef _Float16 half4 __attribute__((ext_vector_type(4)));
typedef float f32x4 __attribute__((ext_vector_type(4)));

#define S_LEN 2048
#define HDIM 64
#define QBLK 64
#define KVBLK 64
#define NT (S_LEN / KVBLK)
#define QRS 258   // qrel row stride (elements)
#define NBH 16    // B*H

__device__ __forceinline__ void load_lds16(const void* g, void* l) {
    __builtin_amdgcn_global_load_lds(
        (const __attribute__((address_space(1))) unsigned int*)g,
        (__attribute__((address_space(3))) unsigned int*)l, 16, 0, 0);
}

// ---------------- pre-pass: K (fp32 row-major) -> Kh (fp16, per-tile swizzled LDS image) ----
// Kh element (bh, t, kv, d) at byte (bh*32+t)*8192 + ((kv*128 + d*2) ^ ((kv&7)<<4))
__global__ __launch_bounds__(256)
void convert_k_kernel(const float* __restrict__ Kg, _Float16* __restrict__ Kh)
{
    const int id = blockIdx.x * 256 + threadIdx.x;       // 262144 total
    const int r  = id >> 3;                               // global row: bh*2048 + kvg
    const int d0 = (id & 7) * 8;
    const float* src = Kg + (size_t)r * HDIM + d0;
    f32x4 f0 = *(const f32x4*)(src);
    f32x4 f1 = *(const f32x4*)(src + 4);
    half8 h;
#pragma unroll
    for (int j = 0; j < 4; ++j) { h[j] = (_Float16)f0[j]; h[j+4] = (_Float16)f1[j]; }
    const int bh = r >> 11, kvg = r & 2047;
    const int t = kvg >> 6, kv = kvg & 63;
    const size_t blk = (size_t)(bh * NT + t) * 8192;
    const int off = (kv * 128 + d0 * 2) ^ ((kv & 7) << 4);
    *(half8*)((char*)Kh + blk + off) = h;
}

// ---------------- pre-pass: V -> Vth (fp16 transposed per-tile swizzled LDS image) --------
// Vth element (bh, t, d, kv) at byte (bh*32+t)*8192 + ((d*128 + kv*2) ^ ((d&7)<<4))
__global__ __launch_bounds__(256)
void convert_v_kernel(const float* __restrict__ Vg, _Float16* __restrict__ Vth)
{
    __shared__ _Float16 tile[KVBLK * HDIM];   // [kv][d] linear
    const int bt = blockIdx.x;                // bh*32 + t
    const int bh = bt >> 5, t = bt & 31;
    const int tid = threadIdx.x;
    {
        const int kv = tid >> 2;
        const int d0 = (tid & 3) * 16;
        const float* src = Vg + ((size_t)bh * S_LEN + t * KVBLK + kv) * HDIM + d0;
        f32x4 f0 = *(const f32x4*)(src);
        f32x4 f1 = *(const f32x4*)(src + 4);
        f32x4 f2 = *(const f32x4*)(src + 8);
        f32x4 f3 = *(const f32x4*)(src + 12);
        half8 h0, h1;
#pragma unroll
        for (int j = 0; j < 4; ++j) {
            h0[j] = (_Float16)f0[j]; h0[j+4] = (_Float16)f1[j];
            h1[j] = (_Float16)f2[j]; h1[j+4] = (_Float16)f3[j];
        }
        *(half8*)&tile[kv * HDIM + d0]     = h0;
        *(half8*)&tile[kv * HDIM + d0 + 8] = h1;
    }
    __syncthreads();
    {
        const int d   = tid >> 2;
        const int kv0 = (tid & 3) * 16;
        half8 o0, o1;
#pragma unroll
        for (int j = 0; j < 8; ++j) {
            o0[j] = tile[(kv0 + j) * HDIM + d];
            o1[j] = tile[(kv0 + 8 + j) * HDIM + d];
        }
        char* base = (char*)Vth + (size_t)bt * 8192;
        const int swz = (d & 7) << 4;
        *(half8*)(base + ((d * 128 + kv0 * 2) ^ swz))      = o0;
        *(half8*)(base + ((d * 128 + kv0 * 2 + 16) ^ swz)) = o1;
    }
}

// ---------------- main attention kernel (v2: pre-converted KV + gload_lds pipeline) -------
__global__ __launch_bounds__(256, 2)
void relattn_v2(const float* __restrict__ Qg, const float* __restrict__ RELg,
                const _Float16* __restrict__ Kh, const _Float16* __restrict__ Vth,
                float* __restrict__ Og)
{
    __shared__ _Float16 Kbuf[2][KVBLK * HDIM];   // 16 KB, swizzled image
    __shared__ _Float16 Vbuf[2][KVBLK * HDIM];   // 16 KB, transposed swizzled image
    __shared__ _Float16 Plds[4][16 * KVBLK];     // 8 KB, per-wave [q=16][kv=64], ^((c&7)<<4)
    __shared__ _Float16 Qrel[QBLK * QRS];        // 33 KB

    const int tid  = threadIdx.x;
    const int wave = tid >> 6;
    const int lane = tid & 63;
    const int c = lane & 15;
    const int g = lane >> 4;

    // XCD-chunked swizzle: 512 blocks = 8 XCDs x 64; same-head blocks share an XCD's L2
    const int wk = ((blockIdx.x & 7) << 6) + (blockIdx.x >> 3);
    const int bh = wk >> 5;
    const int q0 = (wk & 31) * QBLK;

    const size_t hoff = (size_t)bh * S_LEN * HDIM;
    const float* Qh = Qg + hoff;

    // ---- Q fragments (B-operand for swapped QK; also A-operand for qrel GEMM), x0.125 ----
    const int qrow_frag = q0 + wave * 16 + c;
    half8 aq[2];
#pragma unroll
    for (int kc = 0; kc < 2; ++kc) {
        const float* src = Qh + (size_t)qrow_frag * HDIM + kc * 32 + g * 8;
        f32x4 f0 = *(const f32x4*)(src);
        f32x4 f1 = *(const f32x4*)(src + 4);
        half8 h;
#pragma unroll
        for (int j = 0; j < 4; ++j) {
            h[j]     = (_Float16)(f0[j] * 0.125f);
            h[j + 4] = (_Float16)(f1[j] * 0.125f);
        }
        aq[kc] = h;
    }

    // ---- qrel = (Q/8) @ rel_table^T via MFMA, rows owned per wave ----
#pragma unroll 1
    for (int t = 0; t < 17; ++t) {
        f32x4 acc = {0.f, 0.f, 0.f, 0.f};
        int r = t * 16 + c;
        if (r > 256) r = 256;
#pragma unroll
        for (int kc = 0; kc < 2; ++kc) {
            const float* src = RELg + (size_t)r * HDIM + kc * 32 + g * 8;
            f32x4 f0 = *(const f32x4*)(src);
            f32x4 f1 = *(const f32x4*)(src + 4);
            half8 b;
#pragma unroll
            for (int j = 0; j < 4; ++j) { b[j] = (_Float16)f0[j]; b[j+4] = (_Float16)f1[j]; }
            acc = __builtin_amdgcn_mfma_f32_16x16x32_f16(aq[kc], b, acc, 0, 0, 0);
        }
        const int col = t * 16 + c;
        if (col <= 256) {
#pragma unroll
            for (int reg = 0; reg < 4; ++reg)
                Qrel[(wave * 16 + 4 * g + reg) * QRS + col] = (_Float16)acc[reg];
        }
    }
    // per-lane clamped-bias constants for the off-band tiles (q = c row of this wave)
    const float bias_lo = (float)Qrel[(wave * 16 + c) * QRS + 0];
    const float bias_hi = (float)Qrel[(wave * 16 + c) * QRS + 256];

    float m = -1e30f, l = 0.f;
    f32x4 oacc[4];
#pragma unroll
    for (int i = 0; i < 4; ++i) oacc[i] = (f32x4){0.f, 0.f, 0.f, 0.f};

    const char* kbase = (const char*)Kh  + (size_t)(bh * NT) * 8192;
    const char* vbase = (const char*)Vth + (size_t)(bh * NT) * 8192;
    const int goff = wave * 2048 + lane * 16;
    const int loff = wave * 2048;

#define ISSUE(tt, bb) do {                                              \
        const char* kt = kbase + (size_t)(tt) * 8192 + goff;            \
        const char* vt = vbase + (size_t)(tt) * 8192 + goff;            \
        char* kl = (char*)&Kbuf[bb][0] + loff;                          \
        char* vl = (char*)&Vbuf[bb][0] + loff;                          \
        load_lds16(kt,        kl);                                      \
        load_lds16(kt + 1024, kl + 1024);                               \
        load_lds16(vt,        vl);                                      \
        load_lds16(vt + 1024, vl + 1024);                               \
    } while (0)

    ISSUE(0, 0);
    const int swz = (c & 7) << 4;

#pragma unroll 1
    for (int t = 0; t < NT; ++t) {
        const int b = t & 1;
        if (t + 1 < NT) {
            ISSUE(t + 1, b ^ 1);
            asm volatile("s_waitcnt vmcnt(4)" ::: "memory");
        } else {
            asm volatile("s_waitcnt vmcnt(0)" ::: "memory");
        }
        __builtin_amdgcn_s_barrier();
        asm volatile("" ::: "memory");

        const int k0 = t * KVBLK;
        const char* kb = (const char*)&Kbuf[b][0];
        const char* vb = (const char*)&Vbuf[b][0];

        // ---- S^T = K @ Q^T (swapped): row = kv_local, col = q = c ----
        f32x4 sacc[4];
#pragma unroll
        for (int n = 0; n < 4; ++n) sacc[n] = (f32x4){0.f,0.f,0.f,0.f};
#pragma unroll
        for (int kc = 0; kc < 2; ++kc) {
#pragma unroll
            for (int n = 0; n < 4; ++n) {
                half8 ak = *(const half8*)(kb + ((((16*n + c) * 128) + kc*64 + g*16) ^ swz));
                sacc[n] = __builtin_amdgcn_mfma_f32_16x16x32_f16(ak, aq[kc], sacc[n], 0, 0, 0);
            }
        }

        // ---- bias: off-band tiles use per-lane constant; band tiles gather ----
        float sval[4][4];
        if (k0 + 192 <= q0 || k0 >= q0 + 192) {
            const float bias = (k0 < q0) ? bias_lo : bias_hi;
#pragma unroll
            for (int n = 0; n < 4; ++n)
#pragma unroll
                for (int r = 0; r < 4; ++r) sval[n][r] = sacc[n][r] + bias;
        } else {
            const int qg_ = q0 + wave * 16 + c;
            const _Float16* qr = &Qrel[(wave * 16 + c) * QRS];
#pragma unroll
            for (int n = 0; n < 4; ++n) {
#pragma unroll
                for (int r = 0; r < 4; ++r) {
                    int rel = (k0 + 16*n + 4*g + r) - qg_;
                    rel = rel < -128 ? -128 : (rel > 128 ? 128 : rel);
                    sval[n][r] = sacc[n][r] + (float)qr[rel + 128];
                }
            }
        }

        // ---- online softmax, per q-row = c (reduce across g-lanes only) ----
        float mt = sval[0][0];
#pragma unroll
        for (int n = 0; n < 4; ++n)
#pragma unroll
            for (int r = 0; r < 4; ++r) mt = fmaxf(mt, sval[n][r]);
        mt = fmaxf(mt, __shfl_xor(mt, 16, 64));
        mt = fmaxf(mt, __shfl_xor(mt, 32, 64));
        const float mnew = fmaxf(m, mt);
        const float alpha = __expf(m - mnew);
        m = mnew;

        float ps = 0.f;
        char* pb = (char*)&Plds[wave][0];
        const int prow = c * 128;
#pragma unroll
        for (int n = 0; n < 4; ++n) {
            half4 ph;
#pragma unroll
            for (int r = 0; r < 4; ++r) {
                const float pv = __expf(sval[n][r] - m);
                ps += pv;
                ph[r] = (_Float16)pv;
            }
            *(half4*)(pb + ((prow + 32*n + 8*g) ^ swz)) = ph;   // 4 consecutive kv, row c
        }
        ps += __shfl_xor(ps, 16, 64);
        ps += __shfl_xor(ps, 32, 64);
        l = l * alpha + ps;

        // rescale O (alpha for q-row 4g+r lives in lane 20g+r of this wave)
#pragma unroll
        for (int r = 0; r < 4; ++r) {
            const float ar = __shfl(alpha, 20 * g + r, 64);
#pragma unroll
            for (int dn = 0; dn < 4; ++dn) oacc[dn][r] *= ar;
        }

        // ---- O += P @ V ----
        half8 ap[2];
#pragma unroll
        for (int kc = 0; kc < 2; ++kc)
            ap[kc] = *(const half8*)(pb + ((prow + kc*64 + g*16) ^ swz));
#pragma unroll
        for (int kc = 0; kc < 2; ++kc) {
#pragma unroll
            for (int dn = 0; dn < 4; ++dn) {
                half8 bv = *(const half8*)(vb + ((((16*dn + c) * 128) + kc*64 + g*16) ^ swz));
                oacc[dn] = __builtin_amdgcn_mfma_f32_16x16x32_f16(ap[kc], bv, oacc[dn], 0, 0, 0);
            }
        }

        __builtin_amdgcn_s_barrier();
        asm volatile("" ::: "memory");
    }
#undef ISSUE

    // ---- epilogue ----
#pragma unroll
    for (int r = 0; r < 4; ++r) {
        const float linv = 1.0f / __shfl(l, 20 * g + r, 64);
        float* dst = Og + hoff + (size_t)(q0 + wave * 16 + 4 * g + r) * HDIM + c;
#pragma unroll
        for (int dn = 0; dn < 4; ++dn)
            dst[16 * dn] = oacc[dn][r] * linv;
    }
}

// ---------------- fallback (round-1 kernel, used if ws too small) -------------------------
__global__ __launch_bounds__(256, 2)
void relattn_v1(const float* __restrict__ Qg, const float* __restrict__ Kg,
                const float* __restrict__ Vg, const float* __restrict__ RELg,
                float* __restrict__ Og)
{
    __shared__ _Float16 Klds[KVBLK * HDIM];
    __shared__ _Float16 Vt[HDIM * KVBLK];
    __shared__ _Float16 Plds[4][16 * KVBLK];
    __shared__ _Float16 Qrel[QBLK * QRS];

    const int tid  = threadIdx.x;
    const int wave = tid >> 6;
    const int lane = tid & 63;
    const int c = lane & 15;
    const int g = lane >> 4;

    const int bid = blockIdx.x;
    const int bh  = bid >> 5;
    const int q0  = (bid & 31) * QBLK;

    const size_t hoff = (size_t)bh * S_LEN * HDIM;
    const float* Qh = Qg + hoff;
    const float* Kh = Kg + hoff;
    const float* Vh = Vg + hoff;

    const int qrow_frag = q0 + wave * 16 + c;
    half8 aq[2];
#pragma unroll
    for (int kc = 0; kc < 2; ++kc) {
        const float* src = Qh + (size_t)qrow_frag * HDIM + kc * 32 + g * 8;
        f32x4 f0 = *(const f32x4*)(src);
        f32x4 f1 = *(const f32x4*)(src + 4);
        half8 h;
#pragma unroll
        for (int j = 0; j < 4; ++j) {
            h[j]     = (_Float16)(f0[j] * 0.125f);
            h[j + 4] = (_Float16)(f1[j] * 0.125f);
        }
        aq[kc] = h;
    }

#pragma unroll 1
    for (int t = 0; t < 17; ++t) {
        f32x4 acc = {0.f, 0.f, 0.f, 0.f};
        int r = t * 16 + c;
        if (r > 256) r = 256;
#pragma unroll
        for (int kc = 0; kc < 2; ++kc) {
            const float* src = RELg + (size_t)r * HDIM + kc * 32 + g * 8;
            f32x4 f0 = *(const f32x4*)(src);
            f32x4 f1 = *(const f32x4*)(src + 4);
            half8 b;
#pragma unroll
            for (int j = 0; j < 4; ++j) { b[j] = (_Float16)f0[j]; b[j+4] = (_Float16)f1[j]; }
            acc = __builtin_amdgcn_mfma_f32_16x16x32_f16(aq[kc], b, acc, 0, 0, 0);
        }
        const int col = t * 16 + c;
        if (col <= 256) {
#pragma unroll
            for (int reg = 0; reg < 4; ++reg)
                Qrel[(wave * 16 + 4 * g + reg) * QRS + col] = (_Float16)acc[reg];
        }
    }

    float mrow[4], lrow[4];
    f32x4 oacc[4];
#pragma unroll
    for (int i = 0; i < 4; ++i) {
        mrow[i] = -1e30f; lrow[i] = 0.f;
        oacc[i] = (f32x4){0.f, 0.f, 0.f, 0.f};
    }

    for (int k0 = 0; k0 < S_LEN; k0 += KVBLK) {
        __syncthreads();
        {
            const int r  = tid >> 2;
            const int dq = (tid & 3) << 4;
            const float* src = Kh + (size_t)(k0 + r) * HDIM + dq;
            f32x4 f0 = *(const f32x4*)(src);
            f32x4 f1 = *(const f32x4*)(src + 4);
            f32x4 f2 = *(const f32x4*)(src + 8);
            f32x4 f3 = *(const f32x4*)(src + 12);
            half8 h0, h1;
#pragma unroll
            for (int j = 0; j < 4; ++j) {
                h0[j] = (_Float16)f0[j]; h0[j+4] = (_Float16)f1[j];
                h1[j] = (_Float16)f2[j]; h1[j+4] = (_Float16)f3[j];
            }
            const int swz = (r & 7) << 4;
            char* base = (char*)Klds;
            *(half8*)(base + ((r * 128 + dq * 2) ^ swz))      = h0;
            *(half8*)(base + ((r * 128 + dq * 2 + 16) ^ swz)) = h1;
        }
        {
            const int kv = tid & 63;
            const int dbase = (tid >> 6) << 4;
            const float* src = Vh + (size_t)(k0 + kv) * HDIM + dbase;
            f32x4 f0 = *(const f32x4*)(src);
            f32x4 f1 = *(const f32x4*)(src + 4);
            f32x4 f2 = *(const f32x4*)(src + 8);
            f32x4 f3 = *(const f32x4*)(src + 12);
            float vals[16];
#pragma unroll
            for (int j = 0; j < 4; ++j) {
                vals[j] = f0[j]; vals[4+j] = f1[j]; vals[8+j] = f2[j]; vals[12+j] = f3[j];
            }
            char* base = (char*)Vt;
#pragma unroll
            for (int i = 0; i < 16; ++i) {
                const int d = dbase + i;
                const int off = (d * 128 + kv * 2) ^ ((d & 7) << 4);
                *(_Float16*)(base + off) = (_Float16)vals[i];
            }
        }
        __syncthreads();

        f32x4 sacc[4];
#pragma unroll
        for (int n = 0; n < 4; ++n) sacc[n] = (f32x4){0.f,0.f,0.f,0.f};
#pragma unroll
        for (int kc = 0; kc < 2; ++kc) {
#pragma unroll
            for (int n = 0; n < 4; ++n) {
                const int off = (((16*n + c) * 128) + kc * 64 + g * 16) ^ ((c & 7) << 4);
                half8 bk = *(const half8*)((const char*)Klds + off);
                sacc[n] = __builtin_amdgcn_mfma_f32_16x16x32_f16(aq[kc], bk, sacc[n], 0, 0, 0);
            }
        }

        float sval[4][4];
        const int myq0 = q0 + wave * 16 + 4 * g;
#pragma unroll
        for (int n = 0; n < 4; ++n) {
            const int kpos = k0 + 16 * n + c;
#pragma unroll
            for (int reg = 0; reg < 4; ++reg) {
                int rel = kpos - (myq0 + reg);
                rel = rel < -128 ? -128 : (rel > 128 ? 128 : rel);
                const float bias = (float)Qrel[(wave*16 + 4*g + reg) * QRS + (rel + 128)];
                sval[n][reg] = sacc[n][reg] + bias;
            }
        }

        float mt[4];
#pragma unroll
        for (int reg = 0; reg < 4; ++reg) {
            float mp = fmaxf(fmaxf(sval[0][reg], sval[1][reg]),
                             fmaxf(sval[2][reg], sval[3][reg]));
#pragma unroll
            for (int msk = 1; msk < 16; msk <<= 1)
                mp = fmaxf(mp, __shfl_xor(mp, msk, 64));
            mt[reg] = mp;
        }

        float alpha[4], psum[4];
#pragma unroll
        for (int reg = 0; reg < 4; ++reg) {
            const float mn = fmaxf(mrow[reg], mt[reg]);
            alpha[reg] = __expf(mrow[reg] - mn);
            mrow[reg] = mn;
            psum[reg] = 0.f;
        }

        char* pbase = (char*)&Plds[wave][0];
#pragma unroll
        for (int n = 0; n < 4; ++n) {
#pragma unroll
            for (int reg = 0; reg < 4; ++reg) {
                const float pv = __expf(sval[n][reg] - mrow[reg]);
                psum[reg] += pv;
                const int row = 4 * g + reg;
                const int off = (row * 128 + (16 * n + c) * 2) ^ ((row & 7) << 4);
                *(_Float16*)(pbase + off) = (_Float16)pv;
            }
        }

#pragma unroll
        for (int reg = 0; reg < 4; ++reg) {
            float ps = psum[reg];
#pragma unroll
            for (int msk = 1; msk < 16; msk <<= 1)
                ps += __shfl_xor(ps, msk, 64);
            lrow[reg] = lrow[reg] * alpha[reg] + ps;
#pragma unroll
            for (int dn = 0; dn < 4; ++dn) oacc[dn][reg] *= alpha[reg];
        }

        asm volatile("s_waitcnt lgkmcnt(0)" ::: "memory");

        half8 ap[2];
#pragma unroll
        for (int kc = 0; kc < 2; ++kc) {
            const int off = (c * 128 + kc * 64 + g * 16) ^ ((c & 7) << 4);
            ap[kc] = *(const half8*)(pbase + off);
        }
#pragma unroll
        for (int kc = 0; kc < 2; ++kc) {
#pragma unroll
            for (int dn = 0; dn < 4; ++dn) {
                const int drow = 16 * dn + c;
                const int off = (drow * 128 + kc * 64 + g * 16) ^ ((c & 7) << 4);
                half8 bv = *(const half8*)((const char*)Vt + off);
                oacc[dn] = __builtin_amdgcn_mfma_f32_16x16x32_f16(ap[kc], bv, oacc[dn], 0, 0, 0);
            }
        }
    }

#pragma unroll
    for (int reg = 0; reg < 4; ++reg) {
        const float inv = 1.0f / lrow[reg];
        const int row = q0 + wave * 16 + 4 * g + reg;
        float* dst = Og + hoff + (size_t)row * HDIM + c;
#pragma unroll
        for (int dn = 0; dn < 4; ++dn)
            dst[16 * dn] = oacc[dn][reg] * inv;
    }
}

extern "C" void kernel_launch(void* const* d_in, const int* in_sizes, int n_in,
                              void* d_out, int out_size, void* d_ws, size_t ws_size,
                              hipStream_t stream) {
    const float* q   = (const float*)d_in[0];
    const float* k   = (const float*)d_in[1];
    const float* v   = (const float*)d_in[2];
    const float* rel = (const float*)d_in[3];
    float* out = (float*)d_out;
    (void)in_sizes; (void)n_in; (void)out_size;

    const size_t kv_bytes = (size_t)NBH * S_LEN * HDIM * sizeof(_Float16);  // 4 MB each
    if (ws_size >= 2 * kv_bytes) {
        _Float16* Kh  = (_Float16*)d_ws;
        _Float16* Vth = (_Float16*)((char*)d_ws + kv_bytes);
        convert_k_kernel<<<dim3((NBH * S_LEN * HDIM / 8) / 256), 256, 0, stream>>>(k, Kh);
        convert_v_kernel<<<dim3(NBH * NT), 256, 0, stream>>>(v, Vth);
        relattn_v2<<<dim3(NBH * (S_LEN / QBLK)), 256, 0, stream>>>(q, rel, Kh, Vth, out);
    } else {
        relattn_v1<<<dim3(NBH * (S_LEN / QBLK)), 256, 0, stream>>>(q, k, v, rel, out);
    }
}

// Round 3
// 63.493 us; speedup vs baseline: 1.7860x; 1.1665x over previous
//
#include <hip/hip_runtime.h>

typedef _Float16 half8 __attribute__((ext_vector_type(8)));
typedef _Float16 half4 __attribute__((ext_vector_type(4)));
typedef float f32x4 __attribute__((ext_vector_type(4)));

#define S_LEN 2048
#define HDIM 64
#define QBLK 64
#define KVBLK 64
#define NT (S_LEN / KVBLK)
#define QRS 258
#define NBH 16
#define L2E 1.44269504f
#define TSTR 72   // padded LDS stride for V pre-pass transpose (144B, 16B-aligned)

__device__ __forceinline__ void load_lds16(const void* g, void* l) {
    __builtin_amdgcn_global_load_lds(
        (const __attribute__((address_space(1))) unsigned int*)g,
        (__attribute__((address_space(3))) unsigned int*)l, 16, 0, 0);
}

// ---- fused pre-pass ----------------------------------------------------------------
// blocks 0..1023: K fp32 -> Kh fp16 per-tile swizzled image:
//   (bh,t,kv,d) at byte (bh*32+t)*8192 + ((kv*128 + d*2) ^ ((kv&7)<<4))
// blocks 1024..1535: V fp32 -> Vp fp16 pi-permuted transposed image:
//   chunk (d', u=4*kc+g) at byte tile*8192 + ((d'*128 + u*16) ^ ((d'&7)<<4))
//   content = {V[32kc+4g+r][d']}_{r=0..3} ++ {V[32kc+16+4g+r][d']}_{r=0..3}
__global__ __launch_bounds__(256)
void convert_kv_kernel(const float* __restrict__ Kg, const float* __restrict__ Vg,
                       _Float16* __restrict__ Kh, _Float16* __restrict__ Vp)
{
    __shared__ _Float16 tile[KVBLK * TSTR];
    const int bid = blockIdx.x;
    const int tid = threadIdx.x;
    if (bid < 1024) {
        const int id = bid * 256 + tid;
        const int r  = id >> 3;
        const int d0 = (id & 7) * 8;
        const float* src = Kg + (size_t)r * HDIM + d0;
        f32x4 f0 = *(const f32x4*)(src);
        f32x4 f1 = *(const f32x4*)(src + 4);
        half8 h;
#pragma unroll
        for (int j = 0; j < 4; ++j) { h[j] = (_Float16)f0[j]; h[j+4] = (_Float16)f1[j]; }
        const int bh = r >> 11, kvg = r & 2047;
        const int t = kvg >> 6, kv = kvg & 63;
        const size_t blk = (size_t)(bh * NT + t) * 8192;
        const int off = (kv * 128 + d0 * 2) ^ ((kv & 7) << 4);
        *(half8*)((char*)Kh + blk + off) = h;
    } else {
        const int bt = bid - 1024;               // bh*32 + t
        const int bh = bt >> 5, t = bt & 31;
        {
            const int kv = tid >> 2;
            const int d0 = (tid & 3) * 16;
            const float* src = Vg + ((size_t)bh * S_LEN + t * KVBLK + kv) * HDIM + d0;
            f32x4 f0 = *(const f32x4*)(src);
            f32x4 f1 = *(const f32x4*)(src + 4);
            f32x4 f2 = *(const f32x4*)(src + 8);
            f32x4 f3 = *(const f32x4*)(src + 12);
            half8 h0, h1;
#pragma unroll
            for (int j = 0; j < 4; ++j) {
                h0[j] = (_Float16)f0[j]; h0[j+4] = (_Float16)f1[j];
                h1[j] = (_Float16)f2[j]; h1[j+4] = (_Float16)f3[j];
            }
            *(half8*)&tile[kv * TSTR + d0]     = h0;
            *(half8*)&tile[kv * TSTR + d0 + 8] = h1;
        }
        __syncthreads();
        {
            const int dp = tid >> 2;             // d' = 0..63
            const int u0 = (tid & 3) * 2;
            char* base = (char*)Vp + (size_t)bt * 8192;
            const int swz = (dp & 7) << 4;
#pragma unroll
            for (int ui = 0; ui < 2; ++ui) {
                const int u  = u0 + ui;
                const int kc = u >> 2, g = u & 3;
                half8 ch;
#pragma unroll
                for (int r = 0; r < 4; ++r) {
                    ch[r]     = tile[(32*kc + 4*g + r)      * TSTR + dp];
                    ch[4 + r] = tile[(32*kc + 16 + 4*g + r) * TSTR + dp];
                }
                *(half8*)(base + ((dp * 128 + u * 16) ^ swz)) = ch;
            }
        }
    }
}

// ---- main attention kernel (v3) ----------------------------------------------------
__global__ __launch_bounds__(256, 2)
void relattn_v3(const float* __restrict__ Qg, const float* __restrict__ RELg,
                const _Float16* __restrict__ Kh, const _Float16* __restrict__ Vp,
                float* __restrict__ Og)
{
    __shared__ __attribute__((aligned(16))) _Float16 Kbuf[2][4096];  // 16 KB
    __shared__ __attribute__((aligned(16))) _Float16 Vbuf[2][4096];  // 16 KB
    __shared__ __attribute__((aligned(16))) _Float16 Qrel[QBLK * QRS]; // 33 KB

    const int tid  = threadIdx.x;
    const int wave = tid >> 6;
    const int lane = tid & 63;
    const int c = lane & 15;
    const int g = lane >> 4;

    const int wk = ((blockIdx.x & 7) << 6) + (blockIdx.x >> 3);  // XCD-chunked, 512%8==0
    const int bh = wk >> 5;
    const int q0 = (wk & 31) * QBLK;

    const size_t hoff = (size_t)bh * S_LEN * HDIM;

    // ---- Q fragment (x0.125) ----
    const int qg_ = q0 + wave * 16 + c;
    half8 aq[2];
#pragma unroll
    for (int kc = 0; kc < 2; ++kc) {
        const float* src = Qg + hoff + (size_t)qg_ * HDIM + kc * 32 + g * 8;
        f32x4 f0 = *(const f32x4*)(src);
        f32x4 f1 = *(const f32x4*)(src + 4);
        half8 h;
#pragma unroll
        for (int j = 0; j < 4; ++j) {
            h[j]     = (_Float16)(f0[j] * 0.125f);
            h[j + 4] = (_Float16)(f1[j] * 0.125f);
        }
        aq[kc] = h;
    }

    // ---- qrel = (Q/8) @ rel_table^T via MFMA ----
#pragma unroll 1
    for (int t = 0; t < 17; ++t) {
        f32x4 acc = {0.f, 0.f, 0.f, 0.f};
        int r = t * 16 + c;
        if (r > 256) r = 256;
#pragma unroll
        for (int kc = 0; kc < 2; ++kc) {
            const float* src = RELg + (size_t)r * HDIM + kc * 32 + g * 8;
            f32x4 f0 = *(const f32x4*)(src);
            f32x4 f1 = *(const f32x4*)(src + 4);
            half8 b;
#pragma unroll
            for (int j = 0; j < 4; ++j) { b[j] = (_Float16)f0[j]; b[j+4] = (_Float16)f1[j]; }
            acc = __builtin_amdgcn_mfma_f32_16x16x32_f16(aq[kc], b, acc, 0, 0, 0);
        }
        const int col = t * 16 + c;
        if (col <= 256) {
#pragma unroll
            for (int reg = 0; reg < 4; ++reg)
                Qrel[(wave * 16 + 4 * g + reg) * QRS + col] = (_Float16)acc[reg];
        }
    }
    asm volatile("s_waitcnt lgkmcnt(0)" ::: "memory");   // qrel stores visible to own-wave reads
    const _Float16* qr = &Qrel[(wave * 16 + c) * QRS];
    const float bias_lo = (float)qr[0];
    const float bias_hi = (float)qr[256];

    // ---- loop-invariant LDS read pointers (all reads become base + immediate) ----
    const int swz  = (c & 7) << 4;
    const int off0 = (g * 16) ^ swz;
    const int off1 = (64 + g * 16) ^ swz;
    const char* kp0 = (const char*)Kbuf + c * 128 + off0;
    const char* kp1 = (const char*)Kbuf + c * 128 + off1;
    const char* vp0 = (const char*)Vbuf + c * 128 + off0;
    const char* vp1 = (const char*)Vbuf + c * 128 + off1;

    half8 ones;
#pragma unroll
    for (int j = 0; j < 8; ++j) ones[j] = (_Float16)1.0f;

    float m = -1e30f;
    f32x4 l_acc = {0.f, 0.f, 0.f, 0.f};
    f32x4 oacc[4];
#pragma unroll
    for (int i = 0; i < 4; ++i) oacc[i] = (f32x4){0.f, 0.f, 0.f, 0.f};

    const char* kbase = (const char*)Kh + (size_t)(bh * NT) * 8192;
    const char* vbase = (const char*)Vp + (size_t)(bh * NT) * 8192;
    const int goff = wave * 2048 + lane * 16;
    const int loff = wave * 2048;

#define ISSUE(tt, bb) do {                                              \
        const char* kt = kbase + (size_t)(tt) * 8192 + goff;            \
        const char* vt = vbase + (size_t)(tt) * 8192 + goff;            \
        char* kl = (char*)Kbuf + (bb) * 8192 + loff;                    \
        char* vl = (char*)Vbuf + (bb) * 8192 + loff;                    \
        load_lds16(kt,        kl);                                      \
        load_lds16(kt + 1024, kl + 1024);                               \
        load_lds16(vt,        vl);                                      \
        load_lds16(vt + 1024, vl + 1024);                               \
    } while (0)

#define BODY(t, b) do {                                                              \
        if ((t) + 1 < NT) {                                                          \
            ISSUE((t) + 1, (b) ^ 1);                                                 \
            asm volatile("s_waitcnt vmcnt(4)" ::: "memory");                         \
        } else {                                                                     \
            asm volatile("s_waitcnt vmcnt(0)" ::: "memory");                         \
        }                                                                            \
        __builtin_amdgcn_s_barrier();                                                \
        const int k0 = (t) * KVBLK;                                                  \
        f32x4 sacc[4];                                                               \
        _Pragma("unroll")                                                            \
        for (int n = 0; n < 4; ++n) sacc[n] = (f32x4){0.f,0.f,0.f,0.f};              \
        __builtin_amdgcn_s_setprio(1);                                               \
        _Pragma("unroll")                                                            \
        for (int n = 0; n < 4; ++n) {                                                \
            half8 ak0 = *(const half8*)(kp0 + (b) * 8192 + n * 2048);                \
            sacc[n] = __builtin_amdgcn_mfma_f32_16x16x32_f16(ak0, aq[0], sacc[n], 0, 0, 0); \
        }                                                                            \
        _Pragma("unroll")                                                            \
        for (int n = 0; n < 4; ++n) {                                                \
            half8 ak1 = *(const half8*)(kp1 + (b) * 8192 + n * 2048);                \
            sacc[n] = __builtin_amdgcn_mfma_f32_16x16x32_f16(ak1, aq[1], sacc[n], 0, 0, 0); \
        }                                                                            \
        __builtin_amdgcn_s_setprio(0);                                               \
        const bool band = (k0 + 192 > q0) && (k0 < q0 + 192);                        \
        float fold; float mtb;                                                       \
        if (!band) {                                                                 \
            const float bc = (k0 < q0) ? bias_lo : bias_hi;                          \
            float mt = sacc[0][0];                                                   \
            _Pragma("unroll")                                                        \
            for (int n = 0; n < 4; ++n)                                              \
                _Pragma("unroll")                                                    \
                for (int r = 0; r < 4; ++r) mt = fmaxf(mt, sacc[n][r]);              \
            mt = fmaxf(mt, __shfl_xor(mt, 16, 64));                                  \
            mt = fmaxf(mt, __shfl_xor(mt, 32, 64));                                  \
            mtb = mt + bc;                                                           \
            if (!__all(mtb <= m + 8.f)) {                                            \
                const float mnew = fmaxf(m, mtb);                                    \
                const float al = __builtin_amdgcn_exp2f((m - mnew) * L2E);           \
                m = mnew;                                                            \
                _Pragma("unroll")                                                    \
                for (int r = 0; r < 4; ++r) {                                        \
                    const float ar = __shfl(al, 20 * g + r, 64);                     \
                    l_acc[r] *= ar;                                                  \
                    _Pragma("unroll")                                                \
                    for (int dn = 0; dn < 4; ++dn) oacc[dn][r] *= ar;                \
                }                                                                    \
            }                                                                        \
            fold = (bc - m) * L2E;                                                   \
        } else {                                                                     \
            const int base_d = k0 + 4 * g - qg_ + 128;                               \
            float mt = -1e30f;                                                       \
            _Pragma("unroll")                                                        \
            for (int n = 0; n < 4; ++n) {                                            \
                _Pragma("unroll")                                                    \
                for (int r = 0; r < 4; ++r) {                                        \
                    int idx = base_d + 16 * n + r;                                   \
                    idx = idx < 0 ? 0 : (idx > 256 ? 256 : idx);                     \
                    sacc[n][r] += (float)qr[idx];                                    \
                    mt = fmaxf(mt, sacc[n][r]);                                      \
                }                                                                    \
            }                                                                        \
            mt = fmaxf(mt, __shfl_xor(mt, 16, 64));                                  \
            mt = fmaxf(mt, __shfl_xor(mt, 32, 64));                                  \
            mtb = mt;                                                                \
            if (!__all(mtb <= m + 8.f)) {                                            \
                const float mnew = fmaxf(m, mtb);                                    \
                const float al = __builtin_amdgcn_exp2f((m - mnew) * L2E);           \
                m = mnew;                                                            \
                _Pragma("unroll")                                                    \
                for (int r = 0; r < 4; ++r) {                                        \
                    const float ar = __shfl(al, 20 * g + r, 64);                     \
                    l_acc[r] *= ar;                                                  \
                    _Pragma("unroll")                                                \
                    for (int dn = 0; dn < 4; ++dn) oacc[dn][r] *= ar;                \
                }                                                                    \
            }                                                                        \
            fold = -m * L2E;                                                         \
        }                                                                            \
        half4 p4[4];                                                                 \
        _Pragma("unroll")                                                            \
        for (int n = 0; n < 4; ++n) {                                                \
            _Pragma("unroll")                                                        \
            for (int r = 0; r < 4; ++r) {                                            \
                const float pv = __builtin_amdgcn_exp2f(fmaf(sacc[n][r], L2E, fold));\
                p4[n][r] = (_Float16)pv;                                             \
            }                                                                        \
        }                                                                            \
        half8 ap0, ap1;                                                              \
        _Pragma("unroll")                                                            \
        for (int r = 0; r < 4; ++r) {                                                \
            ap0[r] = p4[0][r]; ap0[4 + r] = p4[1][r];                                \
            ap1[r] = p4[2][r]; ap1[4 + r] = p4[3][r];                                \
        }                                                                            \
        __builtin_amdgcn_s_setprio(1);                                               \
        l_acc = __builtin_amdgcn_mfma_f32_16x16x32_f16(ap0, ones, l_acc, 0, 0, 0);   \
        l_acc = __builtin_amdgcn_mfma_f32_16x16x32_f16(ap1, ones, l_acc, 0, 0, 0);   \
        _Pragma("unroll")                                                            \
        for (int dn = 0; dn < 4; ++dn) {                                             \
            half8 bv0 = *(const half8*)(vp0 + (b) * 8192 + dn * 2048);               \
            oacc[dn] = __builtin_amdgcn_mfma_f32_16x16x32_f16(ap0, bv0, oacc[dn], 0, 0, 0); \
        }                                                                            \
        _Pragma("unroll")                                                            \
        for (int dn = 0; dn < 4; ++dn) {                                             \
            half8 bv1 = *(const half8*)(vp1 + (b) * 8192 + dn * 2048);               \
            oacc[dn] = __builtin_amdgcn_mfma_f32_16x16x32_f16(ap1, bv1, oacc[dn], 0, 0, 0); \
        }                                                                            \
        __builtin_amdgcn_s_setprio(0);                                               \
        __builtin_amdgcn_s_barrier();                                                \
    } while (0)

    ISSUE(0, 0);
#pragma unroll 1
    for (int tt = 0; tt < NT; tt += 2) {
        BODY(tt, 0);
        BODY(tt + 1, 1);
    }
#undef BODY
#undef ISSUE

    // ---- epilogue: O[q=4g+r][d=16dn+c] = oacc[dn][r] / l_acc[r] ----
#pragma unroll
    for (int r = 0; r < 4; ++r) {
        const float inv = 1.0f / l_acc[r];
        float* dst = Og + hoff + (size_t)(q0 + wave * 16 + 4 * g + r) * HDIM + c;
#pragma unroll
        for (int dn = 0; dn < 4; ++dn)
            dst[16 * dn] = oacc[dn][r] * inv;
    }
}

// ---- fallback (round-1 kernel, used if ws too small) --------------------------------
__global__ __launch_bounds__(256, 2)
void relattn_v1(const float* __restrict__ Qg, const float* __restrict__ Kg,
                const float* __restrict__ Vg, const float* __restrict__ RELg,
                float* __restrict__ Og)
{
    __shared__ _Float16 Klds[KVBLK * HDIM];
    __shared__ _Float16 Vt[HDIM * KVBLK];
    __shared__ _Float16 Plds[4][16 * KVBLK];
    __shared__ _Float16 Qrel[QBLK * QRS];

    const int tid  = threadIdx.x;
    const int wave = tid >> 6;
    const int lane = tid & 63;
    const int c = lane & 15;
    const int g = lane >> 4;

    const int bid = blockIdx.x;
    const int bh  = bid >> 5;
    const int q0  = (bid & 31) * QBLK;

    const size_t hoff = (size_t)bh * S_LEN * HDIM;
    const float* Qh = Qg + hoff;
    const float* Kh = Kg + hoff;
    const float* Vh = Vg + hoff;

    const int qrow_frag = q0 + wave * 16 + c;
    half8 aq[2];
#pragma unroll
    for (int kc = 0; kc < 2; ++kc) {
        const float* src = Qh + (size_t)qrow_frag * HDIM + kc * 32 + g * 8;
        f32x4 f0 = *(const f32x4*)(src);
        f32x4 f1 = *(const f32x4*)(src + 4);
        half8 h;
#pragma unroll
        for (int j = 0; j < 4; ++j) {
            h[j]     = (_Float16)(f0[j] * 0.125f);
            h[j + 4] = (_Float16)(f1[j] * 0.125f);
        }
        aq[kc] = h;
    }

#pragma unroll 1
    for (int t = 0; t < 17; ++t) {
        f32x4 acc = {0.f, 0.f, 0.f, 0.f};
        int r = t * 16 + c;
        if (r > 256) r = 256;
#pragma unroll
        for (int kc = 0; kc < 2; ++kc) {
            const float* src = RELg + (size_t)r * HDIM + kc * 32 + g * 8;
            f32x4 f0 = *(const f32x4*)(src);
            f32x4 f1 = *(const f32x4*)(src + 4);
            half8 b;
#pragma unroll
            for (int j = 0; j < 4; ++j) { b[j] = (_Float16)f0[j]; b[j+4] = (_Float16)f1[j]; }
            acc = __builtin_amdgcn_mfma_f32_16x16x32_f16(aq[kc], b, acc, 0, 0, 0);
        }
        const int col = t * 16 + c;
        if (col <= 256) {
#pragma unroll
            for (int reg = 0; reg < 4; ++reg)
                Qrel[(wave * 16 + 4 * g + reg) * QRS + col] = (_Float16)acc[reg];
        }
    }

    float mrow[4], lrow[4];
    f32x4 oacc[4];
#pragma unroll
    for (int i = 0; i < 4; ++i) {
        mrow[i] = -1e30f; lrow[i] = 0.f;
        oacc[i] = (f32x4){0.f, 0.f, 0.f, 0.f};
    }

    for (int k0 = 0; k0 < S_LEN; k0 += KVBLK) {
        __syncthreads();
        {
            const int r  = tid >> 2;
            const int dq = (tid & 3) << 4;
            const float* src = Kh + (size_t)(k0 + r) * HDIM + dq;
            f32x4 f0 = *(const f32x4*)(src);
            f32x4 f1 = *(const f32x4*)(src + 4);
            f32x4 f2 = *(const f32x4*)(src + 8);
            f32x4 f3 = *(const f32x4*)(src + 12);
            half8 h0, h1;
#pragma unroll
            for (int j = 0; j < 4; ++j) {
                h0[j] = (_Float16)f0[j]; h0[j+4] = (_Float16)f1[j];
                h1[j] = (_Float16)f2[j]; h1[j+4] = (_Float16)f3[j];
            }
            const int swz = (r & 7) << 4;
            char* base = (char*)Klds;
            *(half8*)(base + ((r * 128 + dq * 2) ^ swz))      = h0;
            *(half8*)(base + ((r * 128 + dq * 2 + 16) ^ swz)) = h1;
        }
        {
            const int kv = tid & 63;
            const int dbase = (tid >> 6) << 4;
            const float* src = Vh + (size_t)(k0 + kv) * HDIM + dbase;
            f32x4 f0 = *(const f32x4*)(src);
            f32x4 f1 = *(const f32x4*)(src + 4);
            f32x4 f2 = *(const f32x4*)(src + 8);
            f32x4 f3 = *(const f32x4*)(src + 12);
            float vals[16];
#pragma unroll
            for (int j = 0; j < 4; ++j) {
                vals[j] = f0[j]; vals[4+j] = f1[j]; vals[8+j] = f2[j]; vals[12+j] = f3[j];
            }
            char* base = (char*)Vt;
#pragma unroll
            for (int i = 0; i < 16; ++i) {
                const int d = dbase + i;
                const int off = (d * 128 + kv * 2) ^ ((d & 7) << 4);
                *(_Float16*)(base + off) = (_Float16)vals[i];
            }
        }
        __syncthreads();

        f32x4 sacc[4];
#pragma unroll
        for (int n = 0; n < 4; ++n) sacc[n] = (f32x4){0.f,0.f,0.f,0.f};
#pragma unroll
        for (int kc = 0; kc < 2; ++kc) {
#pragma unroll
            for (int n = 0; n < 4; ++n) {
                const int off = (((16*n + c) * 128) + kc * 64 + g * 16) ^ ((c & 7) << 4);
                half8 bk = *(const half8*)((const char*)Klds + off);
                sacc[n] = __builtin_amdgcn_mfma_f32_16x16x32_f16(aq[kc], bk, sacc[n], 0, 0, 0);
            }
        }

        float sval[4][4];
        const int myq0 = q0 + wave * 16 + 4 * g;
#pragma unroll
        for (int n = 0; n < 4; ++n) {
            const int kpos = k0 + 16 * n + c;
#pragma unroll
            for (int reg = 0; reg < 4; ++reg) {
                int rel = kpos - (myq0 + reg);
                rel = rel < -128 ? -128 : (rel > 128 ? 128 : rel);
                const float bias = (float)Qrel[(wave*16 + 4*g + reg) * QRS + (rel + 128)];
                sval[n][reg] = sacc[n][reg] + bias;
            }
        }

        float mt[4];
#pragma unroll
        for (int reg = 0; reg < 4; ++reg) {
            float mp = fmaxf(fmaxf(sval[0][reg], sval[1][reg]),
                             fmaxf(sval[2][reg], sval[3][reg]));
#pragma unroll
            for (int msk = 1; msk < 16; msk <<= 1)
                mp = fmaxf(mp, __shfl_xor(mp, msk, 64));
            mt[reg] = mp;
        }

        float alpha[4], psum[4];
#pragma unroll
        for (int reg = 0; reg < 4; ++reg) {
            const float mn = fmaxf(mrow[reg], mt[reg]);
            alpha[reg] = __expf(mrow[reg] - mn);
            mrow[reg] = mn;
            psum[reg] = 0.f;
        }

        char* pbase = (char*)&Plds[wave][0];
#pragma unroll
        for (int n = 0; n < 4; ++n) {
#pragma unroll
            for (int reg = 0; reg < 4; ++reg) {
                const float pv = __expf(sval[n][reg] - mrow[reg]);
                psum[reg] += pv;
                const int row = 4 * g + reg;
                const int off = (row * 128 + (16 * n + c) * 2) ^ ((row & 7) << 4);
                *(_Float16*)(pbase + off) = (_Float16)pv;
            }
        }

#pragma unroll
        for (int reg = 0; reg < 4; ++reg) {
            float ps = psum[reg];
#pragma unroll
            for (int msk = 1; msk < 16; msk <<= 1)
                ps += __shfl_xor(ps, msk, 64);
            lrow[reg] = lrow[reg] * alpha[reg] + ps;
#pragma unroll
            for (int dn = 0; dn < 4; ++dn) oacc[dn][reg] *= alpha[reg];
        }

        asm volatile("s_waitcnt lgkmcnt(0)" ::: "memory");

        half8 ap[2];
#pragma unroll
        for (int kc = 0; kc < 2; ++kc) {
            const int off = (c * 128 + kc * 64 + g * 16) ^ ((c & 7) << 4);
            ap[kc] = *(const half8*)(pbase + off);
        }
#pragma unroll
        for (int kc = 0; kc < 2; ++kc) {
#pragma unroll
            for (int dn = 0; dn < 4; ++dn) {
                const int drow = 16 * dn + c;
                const int off = (drow * 128 + kc * 64 + g * 16) ^ ((c & 7) << 4);
                half8 bv = *(const half8*)((const char*)Vt + off);
                oacc[dn] = __builtin_amdgcn_mfma_f32_16x16x32_f16(ap[kc], bv, oacc[dn], 0, 0, 0);
            }
        }
    }

#pragma unroll
    for (int reg = 0; reg < 4; ++reg) {
        const float inv = 1.0f / lrow[reg];
        const int row = q0 + wave * 16 + 4 * g + reg;
        float* dst = Og + hoff + (size_t)row * HDIM + c;
#pragma unroll
        for (int dn = 0; dn < 4; ++dn)
            dst[16 * dn] = oacc[dn][reg] * inv;
    }
}

extern "C" void kernel_launch(void* const* d_in, const int* in_sizes, int n_in,
                              void* d_out, int out_size, void* d_ws, size_t ws_size,
                              hipStream_t stream) {
    const float* q   = (const float*)d_in[0];
    const float* k   = (const float*)d_in[1];
    const float* v   = (const float*)d_in[2];
    const float* rel = (const float*)d_in[3];
    float* out = (float*)d_out;
    (void)in_sizes; (void)n_in; (void)out_size;

    const size_t kv_bytes = (size_t)NBH * S_LEN * HDIM * sizeof(_Float16);  // 4 MB each
    if (ws_size >= 2 * kv_bytes) {
        _Float16* KhB = (_Float16*)d_ws;
        _Float16* VpB = (_Float16*)((char*)d_ws + kv_bytes);
        convert_kv_kernel<<<dim3(1536), 256, 0, stream>>>(k, v, KhB, VpB);
        relattn_v3<<<dim3(NBH * (S_LEN / QBLK)), 256, 0, stream>>>(q, rel, KhB, VpB, out);
    } else {
        relattn_v1<<<dim3(NBH * (S_LEN / QBLK)), 256, 0, stream>>>(q, k, v, rel, out);
    }
}